// Round 1
// baseline (173.909 us; speedup 1.0000x reference)
//
#include <hip/hip_runtime.h>

#define NB 128      // batch
#define NT 4096     // T
#define DKD 16      // d_k == d_q
#define DW 32       // d_w
#define CHUNKS 8    // T split into chunks; 8 blocks per batch sync via spin
#define TC 512      // NT / CHUNKS
#define BLK 256
#define PT 2        // t-values per thread: TC / BLK

__device__ __forceinline__ float fast_tanh(float x) {
    // tanh(x) = 1 - 2/(e^{2x}+1); exact at +/-inf limits, ~1 ulp rcp error.
    float e = __expf(2.0f * x);
    return 1.0f - 2.0f * __builtin_amdgcn_rcpf(e + 1.0f);
}

// Single fused kernel. Per (batch, chunk) block:
//   1. prefetch key AND value tiles into registers (streams both arrays),
//   2. scores -> p = exp(score) kept in registers (no max-subtract needed:
//      |score| <= ||v_w||_1 + |v_b| ~ 2.6 since tanh is bounded),
//   3. block-reduce partial l and ctx into workspace,
//   4. per-batch spin on a device-scope atomic counter until all 8 chunks
//      have arrived (grid 1024 blocks is guaranteed fully co-resident:
//      __launch_bounds__(256,4) caps VGPR at 128 -> 4 blocks/CU x 256 CU),
//   5. normalize p in registers and write attn ONCE; chunk 0 writes context.
// This removes the second kernel and the 4.2 MB unnormalized-p HBM round-trip.
__global__ __launch_bounds__(BLK, 4) void aa_fused(
    const float* __restrict__ query, const float* __restrict__ key,
    const float* __restrict__ value, const float* __restrict__ W1,
    const float* __restrict__ W2, const float* __restrict__ bias,
    const float* __restrict__ v_w, const float* __restrict__ v_b,
    float* __restrict__ out,            // [0,2048): context; [2048,..): attn
    float* __restrict__ ws_l,           // [NB*CHUNKS]
    float* __restrict__ ws_ctx,         // [NB*CHUNKS*16]
    unsigned int* __restrict__ ws_cnt)  // [NB], zeroed by memset each launch
{
    const int b   = blockIdx.x >> 3;            // blockIdx / CHUNKS
    const int c   = blockIdx.x & (CHUNKS - 1);
    const int tid = threadIdx.x;

    __shared__ float s_w2[DW * DKD];   // [w][d] row-major
    __shared__ float s_comb[DW];       // q_proj[w] + bias (block-uniform)
    __shared__ float s_vw[DW];
    __shared__ float s_rctx[4 * 16];   // per-wave partial ctx
    __shared__ float s_rl[4];
    __shared__ float s_inv;            // 1/L broadcast after spin

    // Preamble: stage W2 (128 float4) and compute q_proj + bias (32 lanes).
    if (tid < 128)
        reinterpret_cast<float4*>(s_w2)[tid] = reinterpret_cast<const float4*>(W2)[tid];
    if (tid >= 128 && tid < 128 + DW) {
        const int w = tid - 128;
        float acc = bias[0];
        const float* q  = query + b * DKD;
        const float* w1 = W1 + w * DKD;
        #pragma unroll
        for (int d = 0; d < DKD; ++d) acc = fmaf(q[d], w1[d], acc);
        s_comb[w] = acc;
        s_vw[w]   = v_w[w];
    }
    __syncthreads();

    const float vb = v_b[0];
    // Thread handles PT consecutive t's: 128 B contiguous per lane.
    const size_t tbase = (size_t)b * NT + (size_t)c * TC + (size_t)tid * PT;
    const float4* kp = reinterpret_cast<const float4*>(key)   + tbase * 4;
    const float4* vp = reinterpret_cast<const float4*>(value) + tbase * 4;

    // Prefetch BOTH key and value up front: 16 global_load_dwordx4 in flight,
    // HBM streams both arrays while the FMA loop runs. ~64 VGPR of data;
    // total stays under the 128-VGPR cap from __launch_bounds__(256,4).
    float4 k0[PT], k1[PT], k2[PT], k3[PT];
    float4 v0[PT], v1[PT], v2[PT], v3[PT];
    #pragma unroll
    for (int j = 0; j < PT; ++j) {
        k0[j] = kp[4*j + 0]; k1[j] = kp[4*j + 1];
        k2[j] = kp[4*j + 2]; k3[j] = kp[4*j + 3];
    }
    #pragma unroll
    for (int j = 0; j < PT; ++j) {
        v0[j] = vp[4*j + 0]; v1[j] = vp[4*j + 1];
        v2[j] = vp[4*j + 2]; v3[j] = vp[4*j + 3];
    }

    float sc[PT];
    #pragma unroll
    for (int j = 0; j < PT; ++j) sc[j] = vb;

    // w-outer, t-inner: each W2 row read from LDS once per PT t's (broadcast).
    #pragma unroll 4
    for (int w = 0; w < DW; ++w) {
        const float4* wr = reinterpret_cast<const float4*>(s_w2 + w * DKD);
        const float4 w0 = wr[0], w1 = wr[1], w2 = wr[2], w3 = wr[3];
        const float cw = s_comb[w];
        const float vw = s_vw[w];
        #pragma unroll
        for (int j = 0; j < PT; ++j) {
            float h = cw;
            h = fmaf(k0[j].x, w0.x, h); h = fmaf(k0[j].y, w0.y, h);
            h = fmaf(k0[j].z, w0.z, h); h = fmaf(k0[j].w, w0.w, h);
            h = fmaf(k1[j].x, w1.x, h); h = fmaf(k1[j].y, w1.y, h);
            h = fmaf(k1[j].z, w1.z, h); h = fmaf(k1[j].w, w1.w, h);
            h = fmaf(k2[j].x, w2.x, h); h = fmaf(k2[j].y, w2.y, h);
            h = fmaf(k2[j].z, w2.z, h); h = fmaf(k2[j].w, w2.w, h);
            h = fmaf(k3[j].x, w3.x, h); h = fmaf(k3[j].y, w3.y, h);
            h = fmaf(k3[j].z, w3.z, h); h = fmaf(k3[j].w, w3.w, h);
            sc[j] = fmaf(fast_tanh(h), vw, sc[j]);
        }
    }

    // p = exp(score); accumulate l and ctx (value already in registers).
    float l = 0.0f;
    float ctx[16];
    #pragma unroll
    for (int d = 0; d < 16; ++d) ctx[d] = 0.0f;

    float p[PT];
    #pragma unroll
    for (int j = 0; j < PT; ++j) {
        p[j] = __expf(sc[j]);
        l += p[j];
        ctx[ 0] = fmaf(p[j], v0[j].x, ctx[ 0]); ctx[ 1] = fmaf(p[j], v0[j].y, ctx[ 1]);
        ctx[ 2] = fmaf(p[j], v0[j].z, ctx[ 2]); ctx[ 3] = fmaf(p[j], v0[j].w, ctx[ 3]);
        ctx[ 4] = fmaf(p[j], v1[j].x, ctx[ 4]); ctx[ 5] = fmaf(p[j], v1[j].y, ctx[ 5]);
        ctx[ 6] = fmaf(p[j], v1[j].z, ctx[ 6]); ctx[ 7] = fmaf(p[j], v1[j].w, ctx[ 7]);
        ctx[ 8] = fmaf(p[j], v2[j].x, ctx[ 8]); ctx[ 9] = fmaf(p[j], v2[j].y, ctx[ 9]);
        ctx[10] = fmaf(p[j], v2[j].z, ctx[10]); ctx[11] = fmaf(p[j], v2[j].w, ctx[11]);
        ctx[12] = fmaf(p[j], v3[j].x, ctx[12]); ctx[13] = fmaf(p[j], v3[j].y, ctx[13]);
        ctx[14] = fmaf(p[j], v3[j].z, ctx[14]); ctx[15] = fmaf(p[j], v3[j].w, ctx[15]);
    }

    // Block reduction: wave shuffle-reduce, then 4 waves via LDS.
    #pragma unroll
    for (int o = 32; o > 0; o >>= 1) l += __shfl_xor(l, o);
    #pragma unroll
    for (int d = 0; d < 16; ++d) {
        #pragma unroll
        for (int o = 32; o > 0; o >>= 1) ctx[d] += __shfl_xor(ctx[d], o);
    }
    const int wave = tid >> 6;
    const int lane = tid & 63;
    if (lane == 0) {
        s_rl[wave] = l;
        #pragma unroll
        for (int d = 0; d < 16; ++d) s_rctx[wave * 16 + d] = ctx[d];
    }
    __syncthreads();

    const int slot = b * CHUNKS + c;
    if (tid < 16)
        __hip_atomic_store(&ws_ctx[slot * 16 + tid],
            s_rctx[tid] + s_rctx[16 + tid] + s_rctx[32 + tid] + s_rctx[48 + tid],
            __ATOMIC_RELAXED, __HIP_MEMORY_SCOPE_AGENT);
    if (tid == 0)
        __hip_atomic_store(&ws_l[slot], s_rl[0] + s_rl[1] + s_rl[2] + s_rl[3],
            __ATOMIC_RELAXED, __HIP_MEMORY_SCOPE_AGENT);
    __syncthreads();   // all partial stores executed before the release below

    // Per-batch arrival counter + spin (tid 0 only; rest park at the barrier).
    // Device-scope fences handle cross-XCD L2 non-coherence.
    if (tid == 0) {
        __threadfence();                       // release partials device-wide
        atomicAdd(&ws_cnt[b], 1u);             // device-scope by default
        while (__hip_atomic_load(&ws_cnt[b], __ATOMIC_RELAXED,
                                 __HIP_MEMORY_SCOPE_AGENT) < CHUNKS)
            __builtin_amdgcn_s_sleep(2);
        __threadfence();                       // acquire: invalidate stale lines
        float L = 0.0f;
        #pragma unroll
        for (int i = 0; i < CHUNKS; ++i)
            L += __hip_atomic_load(&ws_l[b * CHUNKS + i], __ATOMIC_RELAXED,
                                   __HIP_MEMORY_SCOPE_AGENT);
        s_inv = 1.0f / L;
    }
    __syncthreads();
    const float inv = s_inv;

    // Write normalized attn exactly once (coalesced float2 per thread).
    reinterpret_cast<float2*>(out + NB * DKD + (size_t)b * NT + (size_t)c * TC)[tid] =
        make_float2(p[0] * inv, p[1] * inv);

    // Chunk 0 writes context.
    if (c == 0 && tid < DKD) {
        float s = 0.0f;
        #pragma unroll
        for (int i = 0; i < CHUNKS; ++i)
            s += __hip_atomic_load(&ws_ctx[(b * CHUNKS + i) * 16 + tid],
                                   __ATOMIC_RELAXED, __HIP_MEMORY_SCOPE_AGENT);
        out[b * DKD + tid] = s * inv;
    }
}

extern "C" void kernel_launch(void* const* d_in, const int* in_sizes, int n_in,
                              void* d_out, int out_size, void* d_ws, size_t ws_size,
                              hipStream_t stream) {
    const float* query = (const float*)d_in[0];
    const float* key   = (const float*)d_in[1];
    const float* value = (const float*)d_in[2];
    const float* W1    = (const float*)d_in[3];
    const float* W2    = (const float*)d_in[4];
    const float* bias  = (const float*)d_in[5];
    const float* v_w   = (const float*)d_in[6];
    const float* v_b   = (const float*)d_in[7];
    float* out = (float*)d_out;

    // ws layout: [NB uint counters][NB*CHUNKS l][NB*CHUNKS*16 ctx]
    unsigned int* ws_cnt = (unsigned int*)d_ws;
    float* ws_l   = (float*)d_ws + NB;
    float* ws_ctx = ws_l + NB * CHUNKS;

    // Zero the arrival counters each launch (512 B; stream-ordered, graph-
    // capturable memset node; robust to harness re-poisoning of d_ws).
    hipMemsetAsync(d_ws, 0, NB * sizeof(unsigned int), stream);

    aa_fused<<<NB * CHUNKS, BLK, 0, stream>>>(
        query, key, value, W1, W2, bias, v_w, v_b,
        out, ws_l, ws_ctx, ws_cnt);
}

// Round 2
// 166.377 us; speedup vs baseline: 1.0453x; 1.0453x over previous
//
#include <hip/hip_runtime.h>

#define NB 128      // batch
#define NT 4096     // T
#define DKD 16      // d_k == d_q
#define DW 32       // d_w
#define CHUNKS 8    // T split into chunks; last-arriving chunk finishes batch
#define TC 512      // NT / CHUNKS
#define BLK 256
#define PT 2        // t-values per thread: TC / BLK

__device__ __forceinline__ float fast_tanh(float x) {
    // tanh(x) = 1 - 2/(e^{2x}+1); exact at +/-inf limits, ~1 ulp rcp error.
    float e = __expf(2.0f * x);
    return 1.0f - 2.0f * __builtin_amdgcn_rcpf(e + 1.0f);
}

// Single fused kernel, dynamic last-block finisher (NO co-residency assumption,
// no spin — round-1's spin serialized the grid because only ~3 blocks/CU were
// resident vs the 4 required).
// Per (batch, chunk) block:
//   1. stream key+value tile, compute p = exp(score) (no max-subtract needed:
//      |score| <= ||v_w||_1 + |v_b| ~ 2.6 since tanh is bounded),
//   2. write unnormalized p to the attn region, block-reduce (l, ctx) partials
//      to workspace,
//   3. release fence + atomicAdd(counter[b]); the block that sees
//      prev == CHUNKS-1 acquire-fences and becomes the batch finisher:
//      sums L and ctx, writes context, rescales the batch's p row in place.
__global__ __launch_bounds__(BLK, 4) void aa_fused(
    const float* __restrict__ query, const float* __restrict__ key,
    const float* __restrict__ value, const float* __restrict__ W1,
    const float* __restrict__ W2, const float* __restrict__ bias,
    const float* __restrict__ v_w, const float* __restrict__ v_b,
    float* __restrict__ out,            // [0,2048): context; [2048,..): attn
    float* __restrict__ ws_l,           // [NB*CHUNKS]
    float* __restrict__ ws_ctx,         // [NB*CHUNKS*16]
    unsigned int* __restrict__ ws_cnt)  // [NB], zeroed by memset each launch
{
    const int b   = blockIdx.x >> 3;            // blockIdx / CHUNKS
    const int c   = blockIdx.x & (CHUNKS - 1);
    const int tid = threadIdx.x;

    __shared__ float s_w2[DW * DKD];   // [w][d] row-major
    __shared__ float s_comb[DW];       // q_proj[w] + bias (block-uniform)
    __shared__ float s_vw[DW];
    __shared__ float s_rctx[4 * 16];   // per-wave partial ctx
    __shared__ float s_rl[4];
    __shared__ int   s_last;           // am I the batch finisher?
    __shared__ float s_inv;            // 1/L broadcast in finisher

    // Preamble: stage W2 (128 float4) and compute q_proj + bias (32 lanes).
    if (tid < 128)
        reinterpret_cast<float4*>(s_w2)[tid] = reinterpret_cast<const float4*>(W2)[tid];
    if (tid >= 128 && tid < 128 + DW) {
        const int w = tid - 128;
        float acc = bias[0];
        const float* q  = query + b * DKD;
        const float* w1 = W1 + w * DKD;
        #pragma unroll
        for (int d = 0; d < DKD; ++d) acc = fmaf(q[d], w1[d], acc);
        s_comb[w] = acc;
        s_vw[w]   = v_w[w];
    }
    __syncthreads();

    const float vb = v_b[0];
    // Thread handles PT consecutive t's: 128 B contiguous per lane, coalesced.
    const size_t tbase = (size_t)b * NT + (size_t)c * TC + (size_t)tid * PT;
    const float4* kp = reinterpret_cast<const float4*>(key)   + tbase * 4;
    const float4* vp = reinterpret_cast<const float4*>(value) + tbase * 4;

    // Prefetch both key and value tiles: 16 global_load_dwordx4 in flight,
    // HBM streams both arrays while the FMA loop runs.
    float4 k0[PT], k1[PT], k2[PT], k3[PT];
    float4 v0[PT], v1[PT], v2[PT], v3[PT];
    #pragma unroll
    for (int j = 0; j < PT; ++j) {
        k0[j] = kp[4*j + 0]; k1[j] = kp[4*j + 1];
        k2[j] = kp[4*j + 2]; k3[j] = kp[4*j + 3];
    }
    #pragma unroll
    for (int j = 0; j < PT; ++j) {
        v0[j] = vp[4*j + 0]; v1[j] = vp[4*j + 1];
        v2[j] = vp[4*j + 2]; v3[j] = vp[4*j + 3];
    }

    float sc[PT];
    #pragma unroll
    for (int j = 0; j < PT; ++j) sc[j] = vb;

    // w-outer, t-inner: each W2 row read from LDS once per PT t's (broadcast,
    // conflict-free).
    #pragma unroll 4
    for (int w = 0; w < DW; ++w) {
        const float4* wr = reinterpret_cast<const float4*>(s_w2 + w * DKD);
        const float4 w0 = wr[0], w1 = wr[1], w2 = wr[2], w3 = wr[3];
        const float cw = s_comb[w];
        const float vw = s_vw[w];
        #pragma unroll
        for (int j = 0; j < PT; ++j) {
            float h = cw;
            h = fmaf(k0[j].x, w0.x, h); h = fmaf(k0[j].y, w0.y, h);
            h = fmaf(k0[j].z, w0.z, h); h = fmaf(k0[j].w, w0.w, h);
            h = fmaf(k1[j].x, w1.x, h); h = fmaf(k1[j].y, w1.y, h);
            h = fmaf(k1[j].z, w1.z, h); h = fmaf(k1[j].w, w1.w, h);
            h = fmaf(k2[j].x, w2.x, h); h = fmaf(k2[j].y, w2.y, h);
            h = fmaf(k2[j].z, w2.z, h); h = fmaf(k2[j].w, w2.w, h);
            h = fmaf(k3[j].x, w3.x, h); h = fmaf(k3[j].y, w3.y, h);
            h = fmaf(k3[j].z, w3.z, h); h = fmaf(k3[j].w, w3.w, h);
            sc[j] = fmaf(fast_tanh(h), vw, sc[j]);
        }
    }

    // p = exp(score); accumulate l and ctx (value already in registers).
    float l = 0.0f;
    float ctx[16];
    #pragma unroll
    for (int d = 0; d < 16; ++d) ctx[d] = 0.0f;

    float p[PT];
    #pragma unroll
    for (int j = 0; j < PT; ++j) {
        p[j] = __expf(sc[j]);
        l += p[j];
        ctx[ 0] = fmaf(p[j], v0[j].x, ctx[ 0]); ctx[ 1] = fmaf(p[j], v0[j].y, ctx[ 1]);
        ctx[ 2] = fmaf(p[j], v0[j].z, ctx[ 2]); ctx[ 3] = fmaf(p[j], v0[j].w, ctx[ 3]);
        ctx[ 4] = fmaf(p[j], v1[j].x, ctx[ 4]); ctx[ 5] = fmaf(p[j], v1[j].y, ctx[ 5]);
        ctx[ 6] = fmaf(p[j], v1[j].z, ctx[ 6]); ctx[ 7] = fmaf(p[j], v1[j].w, ctx[ 7]);
        ctx[ 8] = fmaf(p[j], v2[j].x, ctx[ 8]); ctx[ 9] = fmaf(p[j], v2[j].y, ctx[ 9]);
        ctx[10] = fmaf(p[j], v2[j].z, ctx[10]); ctx[11] = fmaf(p[j], v2[j].w, ctx[11]);
        ctx[12] = fmaf(p[j], v3[j].x, ctx[12]); ctx[13] = fmaf(p[j], v3[j].y, ctx[13]);
        ctx[14] = fmaf(p[j], v3[j].z, ctx[14]); ctx[15] = fmaf(p[j], v3[j].w, ctx[15]);
    }

    // Write unnormalized p (finisher rescales the whole batch row in place).
    reinterpret_cast<float2*>(out + NB * DKD + (size_t)b * NT + (size_t)c * TC)[tid] =
        make_float2(p[0], p[1]);

    // Block reduction: wave shuffle-reduce, then 4 waves via LDS.
    #pragma unroll
    for (int o = 32; o > 0; o >>= 1) l += __shfl_xor(l, o);
    #pragma unroll
    for (int d = 0; d < 16; ++d) {
        #pragma unroll
        for (int o = 32; o > 0; o >>= 1) ctx[d] += __shfl_xor(ctx[d], o);
    }
    const int wave = tid >> 6;
    const int lane = tid & 63;
    if (lane == 0) {
        s_rl[wave] = l;
        #pragma unroll
        for (int d = 0; d < 16; ++d) s_rctx[wave * 16 + d] = ctx[d];
    }
    __syncthreads();

    const int slot = b * CHUNKS + c;
    if (tid < 16)
        ws_ctx[slot * 16 + tid] =
            s_rctx[tid] + s_rctx[16 + tid] + s_rctx[32 + tid] + s_rctx[48 + tid];
    if (tid == 0)
        ws_l[slot] = s_rl[0] + s_rl[1] + s_rl[2] + s_rl[3];

    // __syncthreads() drains every wave's vmcnt (compiler emits
    // s_waitcnt vmcnt(0) before s_barrier), so ALL p/ws stores of this block
    // are complete at L2 before tid 0's release fence flushes them.
    __syncthreads();
    if (tid == 0) {
        __threadfence();                  // release: flush this XCD's L2
        const unsigned prev = __hip_atomic_fetch_add(
            &ws_cnt[b], 1u, __ATOMIC_ACQ_REL, __HIP_MEMORY_SCOPE_AGENT);
        s_last = (prev == CHUNKS - 1);
        if (s_last) __threadfence();      // acquire: invalidate stale clean lines
    }
    __syncthreads();
    if (!s_last) return;

    // ---- Batch finisher (exactly one block per batch) ----
    if (tid == 0) {
        float L = 0.0f;
        #pragma unroll
        for (int i = 0; i < CHUNKS; ++i) L += ws_l[b * CHUNKS + i];
        s_inv = 1.0f / L;
    }
    __syncthreads();
    const float inv = s_inv;

    // Context output.
    if (tid < DKD) {
        float s = 0.0f;
        #pragma unroll
        for (int i = 0; i < CHUNKS; ++i)
            s += ws_ctx[(b * CHUNKS + i) * 16 + tid];
        out[b * DKD + tid] = s * inv;
    }

    // Rescale the batch's whole p row in place (16 KB: 1024 float4, 4/thread;
    // served from L3 after the writers' release flushes).
    float4* prow = reinterpret_cast<float4*>(out + NB * DKD + (size_t)b * NT);
    #pragma unroll
    for (int i = 0; i < NT / 4 / BLK; ++i) {
        float4 v = prow[tid + i * BLK];
        v.x *= inv; v.y *= inv; v.z *= inv; v.w *= inv;
        prow[tid + i * BLK] = v;
    }
}

extern "C" void kernel_launch(void* const* d_in, const int* in_sizes, int n_in,
                              void* d_out, int out_size, void* d_ws, size_t ws_size,
                              hipStream_t stream) {
    const float* query = (const float*)d_in[0];
    const float* key   = (const float*)d_in[1];
    const float* value = (const float*)d_in[2];
    const float* W1    = (const float*)d_in[3];
    const float* W2    = (const float*)d_in[4];
    const float* bias  = (const float*)d_in[5];
    const float* v_w   = (const float*)d_in[6];
    const float* v_b   = (const float*)d_in[7];
    float* out = (float*)d_out;

    // ws layout: [NB uint counters][NB*CHUNKS l][NB*CHUNKS*16 ctx]
    unsigned int* ws_cnt = (unsigned int*)d_ws;
    float* ws_l   = (float*)d_ws + NB;
    float* ws_ctx = ws_l + NB * CHUNKS;

    // Zero the arrival counters each launch (512 B; stream-ordered,
    // graph-capturable memset node; robust to harness ws poisoning).
    hipMemsetAsync(d_ws, 0, NB * sizeof(unsigned int), stream);

    aa_fused<<<NB * CHUNKS, BLK, 0, stream>>>(
        query, key, value, W1, W2, bias, v_w, v_b,
        out, ws_l, ws_ctx, ws_cnt);
}

// Round 3
// 117.398 us; speedup vs baseline: 1.4814x; 1.4172x over previous
//
#include <hip/hip_runtime.h>

#define NB 128      // batch
#define NT 4096     // T
#define DKD 16      // d_k == d_q
#define DW 32       // d_w
#define CHUNKS 8    // T split into chunks (1024 blocks -> 4 blocks/CU)
#define TC 512      // NT / CHUNKS
#define BLK 256
#define PT 2        // t-values per thread: TC / BLK

__device__ __forceinline__ float fast_tanh(float x) {
    // tanh(x) = 1 - 2/(e^{2x}+1); exact at +/-inf limits, ~1 ulp rcp error.
    float e = __expf(2.0f * x);
    return 1.0f - 2.0f * __builtin_amdgcn_rcpf(e + 1.0f);
}

// Two fence-free kernels. Rounds 1-2 proved single-kernel fusion loses:
// per-block agent-scope fences (L2 writeback/invalidate on gfx950) cost far
// more than the second launch they save (72-90us fused vs ~36us for the pair).
//
// Kernel 1: per (batch, chunk) block. Streams key+value tiles (both prefetched
// up front so HBM sees one long burst), computes p = exp(score) (no
// max-subtract needed: |score| <= ||v_w||_1 + |v_b| ~ 2.6 since tanh is
// bounded), writes unnormalized p, block-reduces partial (l, ctx) to ws.
// Cross-kernel visibility is guaranteed by stream order (kernel-end implicit
// release); no fences anywhere.
__global__ __launch_bounds__(BLK, 4) void aa_score(
    const float* __restrict__ query, const float* __restrict__ key,
    const float* __restrict__ value, const float* __restrict__ W1,
    const float* __restrict__ W2, const float* __restrict__ bias,
    const float* __restrict__ v_w, const float* __restrict__ v_b,
    float* __restrict__ attn,      // out + 2048: unnormalized p written here
    float* __restrict__ ws_l,      // [NB*CHUNKS]
    float* __restrict__ ws_ctx)    // [NB*CHUNKS*16]
{
    const int b   = blockIdx.x >> 3;            // blockIdx / CHUNKS
    const int c   = blockIdx.x & (CHUNKS - 1);
    const int tid = threadIdx.x;

    __shared__ float s_w2[DW * DKD];   // [w][d] row-major
    __shared__ float s_comb[DW];       // q_proj[w] + bias (block-uniform)
    __shared__ float s_vw[DW];
    __shared__ float s_rctx[4 * 16];   // per-wave partial ctx
    __shared__ float s_rl[4];

    // Preamble: stage W2 (128 float4) and compute q_proj + bias (32 lanes).
    if (tid < 128)
        reinterpret_cast<float4*>(s_w2)[tid] = reinterpret_cast<const float4*>(W2)[tid];
    if (tid >= 128 && tid < 128 + DW) {
        const int w = tid - 128;
        float acc = bias[0];
        const float* q  = query + b * DKD;
        const float* w1 = W1 + w * DKD;
        #pragma unroll
        for (int d = 0; d < DKD; ++d) acc = fmaf(q[d], w1[d], acc);
        s_comb[w] = acc;
        s_vw[w]   = v_w[w];
    }
    __syncthreads();

    const float vb = v_b[0];
    // Thread handles PT consecutive t's: 128 B contiguous per lane, coalesced.
    const size_t tbase = (size_t)b * NT + (size_t)c * TC + (size_t)tid * PT;
    const float4* kp = reinterpret_cast<const float4*>(key)   + tbase * 4;
    const float4* vp = reinterpret_cast<const float4*>(value) + tbase * 4;

    // Prefetch BOTH key and value tiles up front: 16 global_load_dwordx4 in
    // flight per thread; HBM streams both arrays while the FMA loop runs.
    // (Round 0 loaded value after compute -> serialized second memory phase.)
    float4 k0[PT], k1[PT], k2[PT], k3[PT];
    float4 v0[PT], v1[PT], v2[PT], v3[PT];
    #pragma unroll
    for (int j = 0; j < PT; ++j) {
        k0[j] = kp[4*j + 0]; k1[j] = kp[4*j + 1];
        k2[j] = kp[4*j + 2]; k3[j] = kp[4*j + 3];
    }
    #pragma unroll
    for (int j = 0; j < PT; ++j) {
        v0[j] = vp[4*j + 0]; v1[j] = vp[4*j + 1];
        v2[j] = vp[4*j + 2]; v3[j] = vp[4*j + 3];
    }

    float sc[PT];
    #pragma unroll
    for (int j = 0; j < PT; ++j) sc[j] = vb;

    // w-outer, t-inner: each W2 row read from LDS once per PT t's (broadcast,
    // conflict-free).
    #pragma unroll 4
    for (int w = 0; w < DW; ++w) {
        const float4* wr = reinterpret_cast<const float4*>(s_w2 + w * DKD);
        const float4 w0 = wr[0], w1 = wr[1], w2 = wr[2], w3 = wr[3];
        const float cw = s_comb[w];
        const float vw = s_vw[w];
        #pragma unroll
        for (int j = 0; j < PT; ++j) {
            float h = cw;
            h = fmaf(k0[j].x, w0.x, h); h = fmaf(k0[j].y, w0.y, h);
            h = fmaf(k0[j].z, w0.z, h); h = fmaf(k0[j].w, w0.w, h);
            h = fmaf(k1[j].x, w1.x, h); h = fmaf(k1[j].y, w1.y, h);
            h = fmaf(k1[j].z, w1.z, h); h = fmaf(k1[j].w, w1.w, h);
            h = fmaf(k2[j].x, w2.x, h); h = fmaf(k2[j].y, w2.y, h);
            h = fmaf(k2[j].z, w2.z, h); h = fmaf(k2[j].w, w2.w, h);
            h = fmaf(k3[j].x, w3.x, h); h = fmaf(k3[j].y, w3.y, h);
            h = fmaf(k3[j].z, w3.z, h); h = fmaf(k3[j].w, w3.w, h);
            sc[j] = fmaf(fast_tanh(h), vw, sc[j]);
        }
    }

    // p = exp(score); accumulate l and ctx (value already in registers).
    float l = 0.0f;
    float ctx[16];
    #pragma unroll
    for (int d = 0; d < 16; ++d) ctx[d] = 0.0f;

    float p[PT];
    #pragma unroll
    for (int j = 0; j < PT; ++j) {
        p[j] = __expf(sc[j]);
        l += p[j];
        ctx[ 0] = fmaf(p[j], v0[j].x, ctx[ 0]); ctx[ 1] = fmaf(p[j], v0[j].y, ctx[ 1]);
        ctx[ 2] = fmaf(p[j], v0[j].z, ctx[ 2]); ctx[ 3] = fmaf(p[j], v0[j].w, ctx[ 3]);
        ctx[ 4] = fmaf(p[j], v1[j].x, ctx[ 4]); ctx[ 5] = fmaf(p[j], v1[j].y, ctx[ 5]);
        ctx[ 6] = fmaf(p[j], v1[j].z, ctx[ 6]); ctx[ 7] = fmaf(p[j], v1[j].w, ctx[ 7]);
        ctx[ 8] = fmaf(p[j], v2[j].x, ctx[ 8]); ctx[ 9] = fmaf(p[j], v2[j].y, ctx[ 9]);
        ctx[10] = fmaf(p[j], v2[j].z, ctx[10]); ctx[11] = fmaf(p[j], v2[j].w, ctx[11]);
        ctx[12] = fmaf(p[j], v3[j].x, ctx[12]); ctx[13] = fmaf(p[j], v3[j].y, ctx[13]);
        ctx[14] = fmaf(p[j], v3[j].z, ctx[14]); ctx[15] = fmaf(p[j], v3[j].w, ctx[15]);
    }

    // Write unnormalized p (kernel 2 normalizes in place).
    reinterpret_cast<float2*>(attn + (size_t)b * NT + (size_t)c * TC)[tid] =
        make_float2(p[0], p[1]);

    // Block reduction: wave shuffle-reduce, then 4 waves via LDS.
    #pragma unroll
    for (int o = 32; o > 0; o >>= 1) l += __shfl_xor(l, o);
    #pragma unroll
    for (int d = 0; d < 16; ++d) {
        #pragma unroll
        for (int o = 32; o > 0; o >>= 1) ctx[d] += __shfl_xor(ctx[d], o);
    }
    const int wave = tid >> 6;
    const int lane = tid & 63;
    if (lane == 0) {
        s_rl[wave] = l;
        #pragma unroll
        for (int d = 0; d < 16; ++d) s_rctx[wave * 16 + d] = ctx[d];
    }
    __syncthreads();
    const int slot = b * CHUNKS + c;
    if (tid < 16)
        ws_ctx[slot * 16 + tid] =
            s_rctx[tid] + s_rctx[16 + tid] + s_rctx[32 + tid] + s_rctx[48 + tid];
    if (tid == 0)
        ws_l[slot] = s_rl[0] + s_rl[1] + s_rl[2] + s_rl[3];
}

// Kernel 2: normalize attn in place by 1/L (L = sum of chunk l's) and write
// context = (sum of chunk ctx's) / L. Each block recomputes L redundantly
// from 8 broadcast loads (L2/L3-resident) — avoids a third kernel.
__global__ __launch_bounds__(BLK) void aa_finish(
    float* __restrict__ out,          // [0,2048) context, [2048,...) attn
    const float* __restrict__ ws_l,
    const float* __restrict__ ws_ctx)
{
    const int b   = blockIdx.x >> 3;
    const int c   = blockIdx.x & (CHUNKS - 1);
    const int tid = threadIdx.x;

    float L = 0.0f;
    #pragma unroll
    for (int i = 0; i < CHUNKS; ++i) L += ws_l[b * CHUNKS + i];
    const float inv = 1.0f / L;

    float2* ap = reinterpret_cast<float2*>(out + NB*DKD + (size_t)b * NT + (size_t)c * TC);
    float2 p = ap[tid];
    p.x *= inv; p.y *= inv;
    ap[tid] = p;

    if (c == 0 && tid < DKD) {
        const float* wc = ws_ctx + b * CHUNKS * 16;
        float s = 0.0f;
        #pragma unroll
        for (int i = 0; i < CHUNKS; ++i) s += wc[i * 16 + tid];
        out[b * DKD + tid] = s * inv;
    }
}

extern "C" void kernel_launch(void* const* d_in, const int* in_sizes, int n_in,
                              void* d_out, int out_size, void* d_ws, size_t ws_size,
                              hipStream_t stream) {
    const float* query = (const float*)d_in[0];
    const float* key   = (const float*)d_in[1];
    const float* value = (const float*)d_in[2];
    const float* W1    = (const float*)d_in[3];
    const float* W2    = (const float*)d_in[4];
    const float* bias  = (const float*)d_in[5];
    const float* v_w   = (const float*)d_in[6];
    const float* v_b   = (const float*)d_in[7];
    float* out = (float*)d_out;

    float* ws_l   = (float*)d_ws;          // NB*CHUNKS floats
    float* ws_ctx = ws_l + NB * CHUNKS;    // NB*CHUNKS*16 floats

    aa_score<<<NB * CHUNKS, BLK, 0, stream>>>(
        query, key, value, W1, W2, bias, v_w, v_b,
        out + NB * DKD, ws_l, ws_ctx);
    aa_finish<<<NB * CHUNKS, BLK, 0, stream>>>(out, ws_l, ws_ctx);
}